// Round 12
// baseline (260.904 us; speedup 1.0000x reference)
//
#include <hip/hip_runtime.h>
#include <hip/hip_bf16.h>
#include <cstdint>

#define N_NODES 50000
#define N_EDGES 1600000
#define DIM 128
#define NREL 8
#define LN_EPS 1e-5f

#define NKEYS (N_NODES * NREL)          // 400000
#define PA_BLOCKS ((N_EDGES + 1023) / 1024)   // 1563 (1024 edges/block)
#define NBIN ((NKEYS + 1023) / 1024)    // 391 coarse bins (key>>10)
#define BH_STRIDE 1600                  // padded blocks-per-bin row stride

#define A_STRIDE 136                    // ushorts per LDS A row (128 + 8 pad)
#define B_STRIDE 136                    // ushorts per LDS B row

#define XB_BLOCKS 6250                  // N_NODES*DIM/4 / 256
#define BT_BLOCKS 576                   // 9*128*128 / 256

typedef unsigned short ushort_t;
typedef short short8 __attribute__((ext_vector_type(8)));
typedef float f32x4 __attribute__((ext_vector_type(4)));
typedef unsigned uintx4 __attribute__((ext_vector_type(4)));

__device__ inline ushort_t f2bf(float f) {
    union { float f; unsigned u; } v; v.f = f;
    unsigned r = (v.u + 0x7FFFu + ((v.u >> 16) & 1u)) >> 16;
    return (ushort_t)r;
}
__device__ inline float bf_lo(unsigned u) {
    union { unsigned u; float f; } v; v.u = u << 16;
    return v.f;
}
__device__ inline float bf_hi(unsigned u) {
    union { unsigned u; float f; } v; v.u = u & 0xffff0000u;
    return v.f;
}

// ---------------------------------------------------------------------------
// Fused prep + Pass A (R17 win): per-1024-edge block LDS histogram over 391
// coarse bins (key>>10) -> block_hist[bin][block]; no global atomics.
// ---------------------------------------------------------------------------
__global__ __launch_bounds__(256) void prep_kernel(const float* __restrict__ x,
                                                   ushort_t* __restrict__ xb,
                                                   const float* __restrict__ W_rel,
                                                   const float* __restrict__ W_root,
                                                   ushort_t* __restrict__ Bt,
                                                   const int* __restrict__ ei,
                                                   const int* __restrict__ et,
                                                   unsigned* __restrict__ block_hist) {
    int b = blockIdx.x;
    int tid = threadIdx.x;
    if (b < PA_BLOCKS) {
        __shared__ unsigned hist[NBIN];
        for (int i = tid; i < NBIN; i += 256) hist[i] = 0u;
        __syncthreads();
        int e = b * 1024 + tid;
#pragma unroll
        for (int q = 0; q < 4; ++q) {
            int eq = e + q * 256;
            if (eq < N_EDGES) {
                int dst = ei[N_EDGES + eq];
                unsigned key = (unsigned)dst * NREL + (unsigned)et[eq];
                atomicAdd(&hist[key >> 10], 1u);
            }
        }
        __syncthreads();
        for (int i = tid; i < NBIN; i += 256)
            block_hist[(size_t)i * BH_STRIDE + b] = hist[i];
    } else if (b < PA_BLOCKS + XB_BLOCKS) {
        int i = (b - PA_BLOCKS) * 256 + tid;              // float4 index
        float4 v = ((const float4*)x)[i];
        unsigned lo = (unsigned)f2bf(v.x) | ((unsigned)f2bf(v.y) << 16);
        unsigned hi = (unsigned)f2bf(v.z) | ((unsigned)f2bf(v.w) << 16);
        ((uint2*)xb)[i] = make_uint2(lo, hi);
    } else if (b < PA_BLOCKS + XB_BLOCKS + BT_BLOCKS) {
        int i = (b - PA_BLOCKS - XB_BLOCKS) * 256 + tid;
        int r   = i >> 14;
        int rem = i & 16383;
        int n   = rem >> 7;
        int k   = rem & 127;
        const float* W = (r < NREL) ? (W_rel + (size_t)r * DIM * DIM) : W_root;
        Bt[i] = f2bf(W[(size_t)k * DIM + n]);
    } else {
        // zero row at node index N_NODES: 128 bf16 = 32 x uint2
        if (tid < 32)
            ((uint2*)(xb + (size_t)N_NODES * DIM))[tid] = make_uint2(0u, 0u);
    }
}

// ---------------------------------------------------------------------------
// Pass A2: per coarse bin, exclusive-scan its 1563 per-block counts in place;
// bin total to bin_tot. One block per bin.
// ---------------------------------------------------------------------------
__global__ __launch_bounds__(256) void scanA2_kernel(unsigned* __restrict__ bh,
                                                     unsigned* __restrict__ bin_tot) {
    __shared__ unsigned lds[256];
    int k = blockIdx.x;
    int tid = threadIdx.x;
    unsigned* row = bh + (size_t)k * BH_STRIDE;
    int base = tid * 7;                               // 7*256 = 1792 >= 1563
    unsigned v[7];
    unsigned s = 0;
#pragma unroll
    for (int j = 0; j < 7; ++j) {
        int i = base + j;
        v[j] = (i < PA_BLOCKS) ? row[i] : 0u;
        s += v[j];
    }
    lds[tid] = s;
    __syncthreads();
    for (int off = 1; off < 256; off <<= 1) {
        unsigned a = (tid >= off) ? lds[tid - off] : 0u;
        __syncthreads();
        lds[tid] += a;
        __syncthreads();
    }
    unsigned ex = lds[tid] - s;
#pragma unroll
    for (int j = 0; j < 7; ++j) {
        int i = base + j;
        if (i < PA_BLOCKS) {
            unsigned t = v[j];
            row[i] = ex;
            ex += t;
        }
    }
    if (tid == 255) bin_tot[k] = lds[255];
}

// ---------------------------------------------------------------------------
// Pass A3: exclusive scan of the 391 bin totals -> absolute bin bases.
// ---------------------------------------------------------------------------
__global__ __launch_bounds__(512) void scanA3_kernel(const unsigned* __restrict__ bin_tot,
                                                     unsigned* __restrict__ bin_base) {
    __shared__ unsigned lds[512];
    int tid = threadIdx.x;
    unsigned v = (tid < NBIN) ? bin_tot[tid] : 0u;
    lds[tid] = v;
    __syncthreads();
    for (int off = 1; off < 512; off <<= 1) {
        unsigned a = (tid >= off) ? lds[tid - off] : 0u;
        __syncthreads();
        lds[tid] += a;
        __syncthreads();
    }
    if (tid < NBIN) bin_base[tid] = lds[tid] - v;
}

// ---------------------------------------------------------------------------
// Pass B: scatter edges into coarse-bin-contiguous records. Per-block LDS
// cursors; local rank via LDS atomic. Record packs (src<<10)|(key&1023).
// ---------------------------------------------------------------------------
__global__ __launch_bounds__(256) void passB_kernel(const int* __restrict__ ei,
                                                    const int* __restrict__ et,
                                                    const unsigned* __restrict__ bh,
                                                    const unsigned* __restrict__ bin_base,
                                                    unsigned* __restrict__ rec) {
    __shared__ unsigned col[NBIN];
    __shared__ unsigned rk[NBIN];
    int b = blockIdx.x;
    int tid = threadIdx.x;
    for (int i = tid; i < NBIN; i += 256) {
        col[i] = bin_base[i] + bh[(size_t)i * BH_STRIDE + b];
        rk[i]  = 0u;
    }
    __syncthreads();
    int e = b * 1024 + tid;
#pragma unroll
    for (int q = 0; q < 4; ++q) {
        int eq = e + q * 256;
        if (eq < N_EDGES) {
            int src = ei[eq];
            int dst = ei[N_EDGES + eq];
            unsigned key = (unsigned)dst * NREL + (unsigned)et[eq];
            unsigned bin = key >> 10;
            unsigned r = atomicAdd(&rk[bin], 1u);
            rec[col[bin] + r] = ((unsigned)src << 10) | (key & 1023u);
        }
    }
}

// ---------------------------------------------------------------------------
// Pass C: per coarse bin fine counting sort (1024 keys). LDS count -> LDS
// scan -> meta (ABSOLUTE starts) -> LDS-cursor scatter of sorted_src.
// ---------------------------------------------------------------------------
__global__ __launch_bounds__(256) void passC_kernel(const unsigned* __restrict__ rec,
                                                    const unsigned* __restrict__ bin_base,
                                                    const unsigned* __restrict__ bin_tot,
                                                    uint2* __restrict__ meta,
                                                    int* __restrict__ sorted_src) {
    __shared__ unsigned cnt[1024];     // counts, then cursors
    __shared__ unsigned lds[256];
    int k = blockIdx.x;
    int tid = threadIdx.x;
    unsigned base = bin_base[k];
    unsigned tot  = bin_tot[k];
    for (int i = tid; i < 1024; i += 256) cnt[i] = 0u;
    __syncthreads();
    for (unsigned i = tid; i < tot; i += 256) {
        unsigned r = rec[base + i];
        atomicAdd(&cnt[r & 1023u], 1u);
    }
    __syncthreads();
    unsigned v[4], incl[4], s = 0;
#pragma unroll
    for (int j = 0; j < 4; ++j) {
        v[j] = cnt[tid * 4 + j];
        s += v[j];
        incl[j] = s;
    }
    lds[tid] = s;
    __syncthreads();
    for (int off = 1; off < 256; off <<= 1) {
        unsigned a = (tid >= off) ? lds[tid - off] : 0u;
        __syncthreads();
        lds[tid] += a;
        __syncthreads();
    }
    unsigned bs = lds[tid] - s;
    unsigned key0 = (unsigned)k * 1024 + tid * 4;
#pragma unroll
    for (int j = 0; j < 4; ++j) {
        unsigned ex = bs + incl[j] - v[j];
        if (key0 + j < NKEYS) meta[key0 + j] = make_uint2(base + ex, v[j]);
    }
    __syncthreads();
#pragma unroll
    for (int j = 0; j < 4; ++j) cnt[tid * 4 + j] = bs + incl[j] - v[j];   // cursors
    __syncthreads();
    for (unsigned i = tid; i < tot; i += 256) {
        unsigned r = rec[base + i];
        unsigned q = r & 1023u;
        unsigned p = atomicAdd(&cnt[q], 1u);
        sorted_src[base + p] = (int)(r >> 10);
    }
}

// ---------------------------------------------------------------------------
// R22 aggregate: THREE buckets per half-wave (12 independent gathers + 3
// index-loads in flight). R14's 4-chain failure was grid shrinkage (1563
// blocks) + max4 padding; 3-chain keeps a big grid (16667 blocks) and only
// +11% padding (E[max3 Poisson4]=5.9 vs pair 5.3/bucket). Named scalars only
// (rule #20). Zero-row padding keeps the fused loop mask-free.
// ---------------------------------------------------------------------------
__global__ __launch_bounds__(256) void aggregate_kernel(const uint2* __restrict__ meta,
                                                        const int* __restrict__ sorted_src,
                                                        const ushort_t* __restrict__ xb,
                                                        ushort_t* __restrict__ h,
                                                        int r0, int cr) {
    int hw = threadIdx.x >> 5;                      // half-wave id 0..7
    int sl = threadIdx.x & 31;                      // lane covers 4 feats
    int g0 = blockIdx.x * 24 + hw * 3;              // first of 3 buckets
    int g1 = g0 + 1;
    int g2 = g0 + 2;
    int total = N_NODES * cr;
    if (g0 >= total) return;

    unsigned st0 = 0u, mc0 = 0u, st1 = 0u, mc1 = 0u, st2 = 0u, mc2 = 0u;
    if (cr == NREL) {
        uint2 md0 = meta[(unsigned)g0];
        st0 = md0.x; mc0 = md0.y;
        if (g1 < total) { uint2 md1 = meta[(unsigned)g1]; st1 = md1.x; mc1 = md1.y; }
        if (g2 < total) { uint2 md2 = meta[(unsigned)g2]; st2 = md2.x; mc2 = md2.y; }
    } else {
        int n0 = g0 / cr, rl0 = g0 - n0 * cr;
        uint2 md0 = meta[(unsigned)n0 * NREL + (unsigned)(r0 + rl0)];
        st0 = md0.x; mc0 = md0.y;
        if (g1 < total) {
            int n1 = g1 / cr, rl1 = g1 - n1 * cr;
            uint2 md1 = meta[(unsigned)n1 * NREL + (unsigned)(r0 + rl1)];
            st1 = md1.x; mc1 = md1.y;
        }
        if (g2 < total) {
            int n2 = g2 / cr, rl2 = g2 - n2 * cr;
            uint2 md2 = meta[(unsigned)n2 * NREL + (unsigned)(r0 + rl2)];
            st2 = md2.x; mc2 = md2.y;
        }
    }

    float a00 = 0.f, a01 = 0.f, a02 = 0.f, a03 = 0.f;
    float a10 = 0.f, a11 = 0.f, a12 = 0.f, a13 = 0.f;
    float a20 = 0.f, a21 = 0.f, a22 = 0.f, a23 = 0.f;
    const char* xbase = (const char*)xb;
    unsigned slb = (unsigned)sl << 3;               // byte offset within row

    unsigned c0 = 0, c1 = 0, c2 = 0;
    while (c0 < mc0 || c1 < mc1 || c2 < mc2) {
        int sv0 = (c0 + (unsigned)sl < mc0) ? sorted_src[st0 + c0 + sl] : N_NODES;
        int sv1 = (c1 + (unsigned)sl < mc1) ? sorted_src[st1 + c1 + sl] : N_NODES;
        int sv2 = (c2 + (unsigned)sl < mc2) ? sorted_src[st2 + c2 + sl] : N_NODES;
        unsigned rem0 = (c0 < mc0) ? ((mc0 - c0 > 32u) ? 32u : (mc0 - c0)) : 0u;
        unsigned rem1 = (c1 < mc1) ? ((mc1 - c1 > 32u) ? 32u : (mc1 - c1)) : 0u;
        unsigned rem2 = (c2 < mc2) ? ((mc2 - c2 > 32u) ? 32u : (mc2 - c2)) : 0u;
        unsigned rm = rem0 > rem1 ? rem0 : rem1;
        rm = rm > rem2 ? rm : rem2;
        for (unsigned j = 0; j < rm; j += 4) {
            int s00 = __shfl(sv0, (int)j,     32);
            int s01 = __shfl(sv0, (int)j + 1, 32);
            int s02 = __shfl(sv0, (int)j + 2, 32);
            int s03 = __shfl(sv0, (int)j + 3, 32);
            int s10 = __shfl(sv1, (int)j,     32);
            int s11 = __shfl(sv1, (int)j + 1, 32);
            int s12 = __shfl(sv1, (int)j + 2, 32);
            int s13 = __shfl(sv1, (int)j + 3, 32);
            int s20 = __shfl(sv2, (int)j,     32);
            int s21 = __shfl(sv2, (int)j + 1, 32);
            int s22 = __shfl(sv2, (int)j + 2, 32);
            int s23 = __shfl(sv2, (int)j + 3, 32);
            uint2 d00 = *(const uint2*)(xbase + ((((unsigned)s00) << 8) | slb));
            uint2 d01 = *(const uint2*)(xbase + ((((unsigned)s01) << 8) | slb));
            uint2 d02 = *(const uint2*)(xbase + ((((unsigned)s02) << 8) | slb));
            uint2 d03 = *(const uint2*)(xbase + ((((unsigned)s03) << 8) | slb));
            uint2 d10 = *(const uint2*)(xbase + ((((unsigned)s10) << 8) | slb));
            uint2 d11 = *(const uint2*)(xbase + ((((unsigned)s11) << 8) | slb));
            uint2 d12 = *(const uint2*)(xbase + ((((unsigned)s12) << 8) | slb));
            uint2 d13 = *(const uint2*)(xbase + ((((unsigned)s13) << 8) | slb));
            uint2 d20 = *(const uint2*)(xbase + ((((unsigned)s20) << 8) | slb));
            uint2 d21 = *(const uint2*)(xbase + ((((unsigned)s21) << 8) | slb));
            uint2 d22 = *(const uint2*)(xbase + ((((unsigned)s22) << 8) | slb));
            uint2 d23 = *(const uint2*)(xbase + ((((unsigned)s23) << 8) | slb));
            a00 += (bf_lo(d00.x) + bf_lo(d01.x)) + (bf_lo(d02.x) + bf_lo(d03.x));
            a01 += (bf_hi(d00.x) + bf_hi(d01.x)) + (bf_hi(d02.x) + bf_hi(d03.x));
            a02 += (bf_lo(d00.y) + bf_lo(d01.y)) + (bf_lo(d02.y) + bf_lo(d03.y));
            a03 += (bf_hi(d00.y) + bf_hi(d01.y)) + (bf_hi(d02.y) + bf_hi(d03.y));
            a10 += (bf_lo(d10.x) + bf_lo(d11.x)) + (bf_lo(d12.x) + bf_lo(d13.x));
            a11 += (bf_hi(d10.x) + bf_hi(d11.x)) + (bf_hi(d12.x) + bf_hi(d13.x));
            a12 += (bf_lo(d10.y) + bf_lo(d11.y)) + (bf_lo(d12.y) + bf_lo(d13.y));
            a13 += (bf_hi(d10.y) + bf_hi(d11.y)) + (bf_hi(d12.y) + bf_hi(d13.y));
            a20 += (bf_lo(d20.x) + bf_lo(d21.x)) + (bf_lo(d22.x) + bf_lo(d23.x));
            a21 += (bf_hi(d20.x) + bf_hi(d21.x)) + (bf_hi(d22.x) + bf_hi(d23.x));
            a22 += (bf_lo(d20.y) + bf_lo(d21.y)) + (bf_lo(d22.y) + bf_lo(d23.y));
            a23 += (bf_hi(d20.y) + bf_hi(d21.y)) + (bf_hi(d22.y) + bf_hi(d23.y));
        }
        c0 += rem0;
        c1 += rem1;
        c2 += rem2;
    }

    float inv0 = 1.0f / fmaxf((float)mc0, 1.0f);
    unsigned lo0 = (unsigned)f2bf(a00 * inv0) | ((unsigned)f2bf(a01 * inv0) << 16);
    unsigned hi0 = (unsigned)f2bf(a02 * inv0) | ((unsigned)f2bf(a03 * inv0) << 16);
    ((uint2*)(h + (size_t)g0 * DIM))[sl] = make_uint2(lo0, hi0);
    if (g1 < total) {
        float inv1 = 1.0f / fmaxf((float)mc1, 1.0f);
        unsigned lo1 = (unsigned)f2bf(a10 * inv1) | ((unsigned)f2bf(a11 * inv1) << 16);
        unsigned hi1 = (unsigned)f2bf(a12 * inv1) | ((unsigned)f2bf(a13 * inv1) << 16);
        ((uint2*)(h + (size_t)g1 * DIM))[sl] = make_uint2(lo1, hi1);
    }
    if (g2 < total) {
        float inv2 = 1.0f / fmaxf((float)mc2, 1.0f);
        unsigned lo2 = (unsigned)f2bf(a20 * inv2) | ((unsigned)f2bf(a21 * inv2) << 16);
        unsigned hi2 = (unsigned)f2bf(a22 * inv2) | ((unsigned)f2bf(a23 * inv2) << 16);
        ((uint2*)(h + (size_t)g2 * DIM))[sl] = make_uint2(lo2, hi2);
    }
}

// ---------------------------------------------------------------------------
// LDS-staged MFMA GEMM + fused bias+LN+ReLU, register-prefetch across the
// rel loop (R18 exact form, measured 249.6 total). R21's XOR swizzle was a
// provable no-op (b128 reads have a structural 8-access/bank floor) and
// measured -6 us; reverted.
// ---------------------------------------------------------------------------
__global__ __launch_bounds__(512) void gemm_ln_kernel(const ushort_t* __restrict__ h,
                                                      int cr, int r0,
                                                      const ushort_t* __restrict__ xb,
                                                      const ushort_t* __restrict__ Bt,
                                                      int include_root,
                                                      const float* __restrict__ bias,
                                                      const float* __restrict__ gamma,
                                                      const float* __restrict__ beta,
                                                      float* __restrict__ out,
                                                      int accumulate, int do_ln) {
    __shared__ __align__(16) ushort_t As[128 * A_STRIDE];   // 34.8 KB
    __shared__ __align__(16) ushort_t Bs[128 * B_STRIDE];   // 34.8 KB

    int tid  = threadIdx.x;
    int w    = tid >> 6;          // 0..7
    int lane = tid & 63;
    int m    = lane & 15;
    int quad = lane >> 4;
    int n0   = blockIdx.x * 128;

    f32x4 acc[8];
#pragma unroll
    for (int j = 0; j < 8; ++j) acc[j] = (f32x4){0.f, 0.f, 0.f, 0.f};

    int nrel = cr + include_root;

    // per-thread staging chunk coords (4 chunks, 16B each)
    int rowc[4], chc[4];
#pragma unroll
    for (int p = 0; p < 4; ++p) {
        int c = tid + 512 * p;
        rowc[p] = c >> 4;
        chc[p]  = c & 15;
    }

    uintx4 ra[4], rb[4];
    auto loadRel = [&](int rr) {
        int rel = (rr < cr) ? (r0 + rr) : NREL;
#pragma unroll
        for (int p = 0; p < 4; ++p) {
            rb[p] = *(const uintx4*)(Bt + ((size_t)rel * DIM + rowc[p]) * DIM + chc[p] * 8);
            uintx4 v = (uintx4){0u, 0u, 0u, 0u};
            int node = n0 + rowc[p];
            if (node < N_NODES) {
                const ushort_t* src = (rr < cr)
                    ? (h + ((size_t)node * cr + rr) * DIM)
                    : (xb + (size_t)node * DIM);
                v = *(const uintx4*)(src + chc[p] * 8);
            }
            ra[p] = v;
        }
    };
    auto writeLDS = [&]() {
#pragma unroll
        for (int p = 0; p < 4; ++p) {
            *(uintx4*)&Bs[rowc[p] * B_STRIDE + chc[p] * 8] = rb[p];
            *(uintx4*)&As[rowc[p] * A_STRIDE + chc[p] * 8] = ra[p];
        }
    };

    // prologue: stage rel 0
    loadRel(0);
    writeLDS();
    __syncthreads();

    for (int rr = 0; rr < nrel; ++rr) {
        // issue next rel's loads BEFORE the MFMA phase (latency hides under MFMA)
        if (rr + 1 < nrel) loadRel(rr + 1);

        // ---- 32 MFMA per wave ----
#pragma unroll
        for (int t = 0; t < 4; ++t) {
            short8 af = *(const short8*)&As[(w * 16 + m) * A_STRIDE + t * 32 + quad * 8];
#pragma unroll
            for (int j = 0; j < 8; ++j) {
                short8 bf = *(const short8*)&Bs[(j * 16 + m) * B_STRIDE + t * 32 + quad * 8];
                acc[j] = __builtin_amdgcn_mfma_f32_16x16x32_bf16(af, bf, acc[j], 0, 0, 0);
            }
        }
        __syncthreads();                 // all LDS reads of this rel done
        if (rr + 1 < nrel) {
            writeLDS();                  // regs (load-complete by waitcnt) -> LDS
            __syncthreads();             // LDS ready for next rel
        }
    }

    // ---- epilogue ----
    if (do_ln) {
        float bj[8], gj[8], btj[8];
#pragma unroll
        for (int j = 0; j < 8; ++j) {
            bj[j]  = bias[j * 16 + m];
            gj[j]  = gamma[j * 16 + m];
            btj[j] = beta[j * 16 + m];
        }
#pragma unroll
        for (int i = 0; i < 4; ++i) {
            float s = 0.f, sq = 0.f;
#pragma unroll
            for (int j = 0; j < 8; ++j) {
                float v = acc[j][i] + bj[j];
                s  += v;
                sq += v * v;
            }
#pragma unroll
            for (int off = 1; off < 16; off <<= 1) {
                s  += __shfl_xor(s, off, 64);
                sq += __shfl_xor(sq, off, 64);
            }
            float mean = s * (1.0f / DIM);
            float var  = sq * (1.0f / DIM) - mean * mean;
            float rstd = rsqrtf(var + LN_EPS);
            int node = n0 + w * 16 + quad * 4 + i;
            if (node < N_NODES) {
#pragma unroll
                for (int j = 0; j < 8; ++j) {
                    float v = acc[j][i] + bj[j];
                    v = (v - mean) * rstd * gj[j] + btj[j];
                    out[(size_t)node * DIM + j * 16 + m] = fmaxf(v, 0.f);
                }
            }
        }
    } else {
#pragma unroll
        for (int i = 0; i < 4; ++i) {
            int node = n0 + w * 16 + quad * 4 + i;
            if (node < N_NODES) {
#pragma unroll
                for (int j = 0; j < 8; ++j) {
                    size_t o = (size_t)node * DIM + j * 16 + m;
                    float v = acc[j][i];
                    if (accumulate) v += out[o];
                    out[o] = v;
                }
            }
        }
    }
}

// ---------------------------------------------------------------------------
// Standalone bias + LayerNorm + ReLU (fallback for chunked path).
// ---------------------------------------------------------------------------
__global__ __launch_bounds__(256) void ln_kernel(float* __restrict__ out,
                                                 const float* __restrict__ bias,
                                                 const float* __restrict__ gamma,
                                                 const float* __restrict__ beta) {
    int row  = blockIdx.x * 4 + (threadIdx.x >> 6);
    int lane = threadIdx.x & 63;
    if (row >= N_NODES) return;
    float2 v = *(float2*)(out + (size_t)row * DIM + lane * 2);
    float2 bi = *(const float2*)(bias + lane * 2);
    v.x += bi.x;
    v.y += bi.y;
    float s  = v.x + v.y;
    float sq = v.x * v.x + v.y * v.y;
#pragma unroll
    for (int off = 32; off > 0; off >>= 1) {
        s  += __shfl_xor(s, off, 64);
        sq += __shfl_xor(sq, off, 64);
    }
    float mean = s * (1.0f / DIM);
    float var  = sq * (1.0f / DIM) - mean * mean;
    float rstd = rsqrtf(var + LN_EPS);
    float2 g = *(const float2*)(gamma + lane * 2);
    float2 b = *(const float2*)(beta + lane * 2);
    v.x = fmaxf((v.x - mean) * rstd * g.x + b.x, 0.f);
    v.y = fmaxf((v.y - mean) * rstd * g.y + b.y, 0.f);
    *(float2*)(out + (size_t)row * DIM + lane * 2) = v;
}

// ---------------------------------------------------------------------------
extern "C" void kernel_launch(void* const* d_in, const int* in_sizes, int n_in,
                              void* d_out, int out_size, void* d_ws, size_t ws_size,
                              hipStream_t stream) {
    const float* x      = (const float*)d_in[0];
    const int*   ei     = (const int*)d_in[1];
    const int*   et     = (const int*)d_in[2];
    const float* W_rel  = (const float*)d_in[4];
    const float* W_root = (const float*)d_in[5];
    const float* bias   = (const float*)d_in[6];
    const float* gamma  = (const float*)d_in[7];
    const float* beta   = (const float*)d_in[8];
    float*       out    = (float*)d_out;

    // ---- workspace layout ----
    char* ws = (char*)d_ws;
    size_t off = 0;
    auto alloc = [&](size_t bytes) { char* p = ws + off; off = (off + bytes + 255) & ~(size_t)255; return p; };
    unsigned* block_hist = (unsigned*)alloc((size_t)NBIN * BH_STRIDE * 4);   // 2.5 MB
    unsigned* bin_tot    = (unsigned*)alloc((size_t)NBIN * 4);
    unsigned* bin_base   = (unsigned*)alloc((size_t)NBIN * 4);
    unsigned* rec        = (unsigned*)alloc((size_t)N_EDGES * 4);            // 6.4 MB
    uint2*    meta       = (uint2*)alloc((size_t)NKEYS * 8);                 // 3.2 MB
    int*      sorted_src = (int*)alloc((size_t)N_EDGES * 4);                 // 6.4 MB
    ushort_t* Bt         = (ushort_t*)alloc((size_t)9 * DIM * DIM * 2);
    ushort_t* xb         = (ushort_t*)alloc((size_t)(N_NODES + 1) * DIM * 2);  // +1 zero row
    size_t fixedOff = off;
    ushort_t* h = (ushort_t*)(ws + fixedOff);
    size_t availB = ws_size > fixedOff ? ws_size - fixedOff : 0;
    size_t perRel = (size_t)N_NODES * DIM * 2;   // 12.8 MB per relation (bf16)
    int chunkR = (int)(availB / perRel);
    if (chunkR > NREL) chunkR = NREL;
    if (chunkR < 1)    chunkR = 1;

    // ---- atomic-free two-level counting sort + prep ----
    prep_kernel<<<PA_BLOCKS + XB_BLOCKS + BT_BLOCKS + 1, 256, 0, stream>>>(
        x, xb, W_rel, W_root, Bt, ei, et, block_hist);
    scanA2_kernel<<<NBIN, 256, 0, stream>>>(block_hist, bin_tot);
    scanA3_kernel<<<1, 512, 0, stream>>>(bin_tot, bin_base);
    passB_kernel<<<PA_BLOCKS, 256, 0, stream>>>(ei, et, block_hist, bin_base, rec);
    passC_kernel<<<NBIN, 256, 0, stream>>>(rec, bin_base, bin_tot, meta, sorted_src);

    int gemmGrid = (N_NODES + 127) / 128;   // 391 blocks

    if (chunkR >= NREL) {
        int nbuck = N_NODES * NREL;
        aggregate_kernel<<<(nbuck + 23) / 24, 256, 0, stream>>>(meta, sorted_src,
                                                                xb, h, 0, NREL);
        gemm_ln_kernel<<<gemmGrid, 512, 0, stream>>>(h, NREL, 0, xb, Bt, 1,
                                                     bias, gamma, beta, out, 0, 1);
    } else {
        for (int r0 = 0; r0 < NREL; r0 += chunkR) {
            int cr = (NREL - r0 < chunkR) ? (NREL - r0) : chunkR;
            int nbuck = N_NODES * cr;
            aggregate_kernel<<<(nbuck + 23) / 24, 256, 0, stream>>>(meta, sorted_src,
                                                                    xb, h, r0, cr);
            int include_root = (r0 + cr == NREL) ? 1 : 0;
            gemm_ln_kernel<<<gemmGrid, 512, 0, stream>>>(h, cr, r0, xb, Bt, include_root,
                                                         bias, gamma, beta, out,
                                                         r0 > 0 ? 1 : 0, 0);
        }
        ln_kernel<<<(N_NODES + 3) / 4, 256, 0, stream>>>(out, bias, gamma, beta);
    }
}

// Round 14
// 252.016 us; speedup vs baseline: 1.0353x; 1.0353x over previous
//
#include <hip/hip_runtime.h>
#include <hip/hip_bf16.h>
#include <cstdint>

#define N_NODES 50000
#define N_EDGES 1600000
#define DIM 128
#define NREL 8
#define LN_EPS 1e-5f

#define NKEYS (N_NODES * NREL)          // 400000
#define PA_BLOCKS ((N_EDGES + 1023) / 1024)   // 1563 (1024 edges/block)
#define NBIN ((NKEYS + 1023) / 1024)    // 391 coarse bins (key>>10)
#define BH_STRIDE 1600                  // padded blocks-per-bin row stride

#define A_STRIDE 136                    // ushorts per LDS A row (128 + 8 pad)
#define B_STRIDE 136                    // ushorts per LDS B row

#define XB_BLOCKS 6250                  // N_NODES*DIM/4 / 256
#define BT_BLOCKS 576                   // 9*128*128 / 256

typedef unsigned short ushort_t;
typedef short short8 __attribute__((ext_vector_type(8)));
typedef float f32x4 __attribute__((ext_vector_type(4)));
typedef unsigned uintx4 __attribute__((ext_vector_type(4)));

__device__ inline ushort_t f2bf(float f) {
    union { float f; unsigned u; } v; v.f = f;
    unsigned r = (v.u + 0x7FFFu + ((v.u >> 16) & 1u)) >> 16;
    return (ushort_t)r;
}
__device__ inline float bf_lo(unsigned u) {
    union { unsigned u; float f; } v; v.u = u << 16;
    return v.f;
}
__device__ inline float bf_hi(unsigned u) {
    union { unsigned u; float f; } v; v.u = u & 0xffff0000u;
    return v.f;
}

// ---------------------------------------------------------------------------
// Fused prep + Pass A (R17 win): per-1024-edge block LDS histogram over 391
// coarse bins (key>>10) -> block_hist[bin][block]; no global atomics.
// ---------------------------------------------------------------------------
__global__ __launch_bounds__(256) void prep_kernel(const float* __restrict__ x,
                                                   ushort_t* __restrict__ xb,
                                                   const float* __restrict__ W_rel,
                                                   const float* __restrict__ W_root,
                                                   ushort_t* __restrict__ Bt,
                                                   const int* __restrict__ ei,
                                                   const int* __restrict__ et,
                                                   unsigned* __restrict__ block_hist) {
    int b = blockIdx.x;
    int tid = threadIdx.x;
    if (b < PA_BLOCKS) {
        __shared__ unsigned hist[NBIN];
        for (int i = tid; i < NBIN; i += 256) hist[i] = 0u;
        __syncthreads();
        int e = b * 1024 + tid;
#pragma unroll
        for (int q = 0; q < 4; ++q) {
            int eq = e + q * 256;
            if (eq < N_EDGES) {
                int dst = ei[N_EDGES + eq];
                unsigned key = (unsigned)dst * NREL + (unsigned)et[eq];
                atomicAdd(&hist[key >> 10], 1u);
            }
        }
        __syncthreads();
        for (int i = tid; i < NBIN; i += 256)
            block_hist[(size_t)i * BH_STRIDE + b] = hist[i];
    } else if (b < PA_BLOCKS + XB_BLOCKS) {
        int i = (b - PA_BLOCKS) * 256 + tid;              // float4 index
        float4 v = ((const float4*)x)[i];
        unsigned lo = (unsigned)f2bf(v.x) | ((unsigned)f2bf(v.y) << 16);
        unsigned hi = (unsigned)f2bf(v.z) | ((unsigned)f2bf(v.w) << 16);
        ((uint2*)xb)[i] = make_uint2(lo, hi);
    } else if (b < PA_BLOCKS + XB_BLOCKS + BT_BLOCKS) {
        int i = (b - PA_BLOCKS - XB_BLOCKS) * 256 + tid;
        int r   = i >> 14;
        int rem = i & 16383;
        int n   = rem >> 7;
        int k   = rem & 127;
        const float* W = (r < NREL) ? (W_rel + (size_t)r * DIM * DIM) : W_root;
        Bt[i] = f2bf(W[(size_t)k * DIM + n]);
    } else {
        // zero row at node index N_NODES: 128 bf16 = 32 x uint2
        if (tid < 32)
            ((uint2*)(xb + (size_t)N_NODES * DIM))[tid] = make_uint2(0u, 0u);
    }
}

// ---------------------------------------------------------------------------
// Pass A2: per coarse bin, exclusive-scan its 1563 per-block counts in place;
// bin total to bin_tot. One block per bin.
// ---------------------------------------------------------------------------
__global__ __launch_bounds__(256) void scanA2_kernel(unsigned* __restrict__ bh,
                                                     unsigned* __restrict__ bin_tot) {
    __shared__ unsigned lds[256];
    int k = blockIdx.x;
    int tid = threadIdx.x;
    unsigned* row = bh + (size_t)k * BH_STRIDE;
    int base = tid * 7;                               // 7*256 = 1792 >= 1563
    unsigned v[7];
    unsigned s = 0;
#pragma unroll
    for (int j = 0; j < 7; ++j) {
        int i = base + j;
        v[j] = (i < PA_BLOCKS) ? row[i] : 0u;
        s += v[j];
    }
    lds[tid] = s;
    __syncthreads();
    for (int off = 1; off < 256; off <<= 1) {
        unsigned a = (tid >= off) ? lds[tid - off] : 0u;
        __syncthreads();
        lds[tid] += a;
        __syncthreads();
    }
    unsigned ex = lds[tid] - s;
#pragma unroll
    for (int j = 0; j < 7; ++j) {
        int i = base + j;
        if (i < PA_BLOCKS) {
            unsigned t = v[j];
            row[i] = ex;
            ex += t;
        }
    }
    if (tid == 255) bin_tot[k] = lds[255];
}

// ---------------------------------------------------------------------------
// Pass A3: exclusive scan of the 391 bin totals -> absolute bin bases.
// ---------------------------------------------------------------------------
__global__ __launch_bounds__(512) void scanA3_kernel(const unsigned* __restrict__ bin_tot,
                                                     unsigned* __restrict__ bin_base) {
    __shared__ unsigned lds[512];
    int tid = threadIdx.x;
    unsigned v = (tid < NBIN) ? bin_tot[tid] : 0u;
    lds[tid] = v;
    __syncthreads();
    for (int off = 1; off < 512; off <<= 1) {
        unsigned a = (tid >= off) ? lds[tid - off] : 0u;
        __syncthreads();
        lds[tid] += a;
        __syncthreads();
    }
    if (tid < NBIN) bin_base[tid] = lds[tid] - v;
}

// ---------------------------------------------------------------------------
// Pass B: scatter edges into coarse-bin-contiguous records. Per-block LDS
// cursors; local rank via LDS atomic. Record packs (src<<10)|(key&1023).
// ---------------------------------------------------------------------------
__global__ __launch_bounds__(256) void passB_kernel(const int* __restrict__ ei,
                                                    const int* __restrict__ et,
                                                    const unsigned* __restrict__ bh,
                                                    const unsigned* __restrict__ bin_base,
                                                    unsigned* __restrict__ rec) {
    __shared__ unsigned col[NBIN];
    __shared__ unsigned rk[NBIN];
    int b = blockIdx.x;
    int tid = threadIdx.x;
    for (int i = tid; i < NBIN; i += 256) {
        col[i] = bin_base[i] + bh[(size_t)i * BH_STRIDE + b];
        rk[i]  = 0u;
    }
    __syncthreads();
    int e = b * 1024 + tid;
#pragma unroll
    for (int q = 0; q < 4; ++q) {
        int eq = e + q * 256;
        if (eq < N_EDGES) {
            int src = ei[eq];
            int dst = ei[N_EDGES + eq];
            unsigned key = (unsigned)dst * NREL + (unsigned)et[eq];
            unsigned bin = key >> 10;
            unsigned r = atomicAdd(&rk[bin], 1u);
            rec[col[bin] + r] = ((unsigned)src << 10) | (key & 1023u);
        }
    }
}

// ---------------------------------------------------------------------------
// Pass C: per coarse bin fine counting sort (1024 keys). LDS count -> LDS
// scan -> meta (ABSOLUTE starts) -> LDS-cursor scatter of sorted_src.
// ---------------------------------------------------------------------------
__global__ __launch_bounds__(256) void passC_kernel(const unsigned* __restrict__ rec,
                                                    const unsigned* __restrict__ bin_base,
                                                    const unsigned* __restrict__ bin_tot,
                                                    uint2* __restrict__ meta,
                                                    int* __restrict__ sorted_src) {
    __shared__ unsigned cnt[1024];     // counts, then cursors
    __shared__ unsigned lds[256];
    int k = blockIdx.x;
    int tid = threadIdx.x;
    unsigned base = bin_base[k];
    unsigned tot  = bin_tot[k];
    for (int i = tid; i < 1024; i += 256) cnt[i] = 0u;
    __syncthreads();
    for (unsigned i = tid; i < tot; i += 256) {
        unsigned r = rec[base + i];
        atomicAdd(&cnt[r & 1023u], 1u);
    }
    __syncthreads();
    unsigned v[4], incl[4], s = 0;
#pragma unroll
    for (int j = 0; j < 4; ++j) {
        v[j] = cnt[tid * 4 + j];
        s += v[j];
        incl[j] = s;
    }
    lds[tid] = s;
    __syncthreads();
    for (int off = 1; off < 256; off <<= 1) {
        unsigned a = (tid >= off) ? lds[tid - off] : 0u;
        __syncthreads();
        lds[tid] += a;
        __syncthreads();
    }
    unsigned bs = lds[tid] - s;
    unsigned key0 = (unsigned)k * 1024 + tid * 4;
#pragma unroll
    for (int j = 0; j < 4; ++j) {
        unsigned ex = bs + incl[j] - v[j];
        if (key0 + j < NKEYS) meta[key0 + j] = make_uint2(base + ex, v[j]);
    }
    __syncthreads();
#pragma unroll
    for (int j = 0; j < 4; ++j) cnt[tid * 4 + j] = bs + incl[j] - v[j];   // cursors
    __syncthreads();
    for (unsigned i = tid; i < tot; i += 256) {
        unsigned r = rec[base + i];
        unsigned q = r & 1023u;
        unsigned p = atomicAdd(&cnt[q], 1u);
        sorted_src[base + p] = (int)(r >> 10);
    }
}

// ---------------------------------------------------------------------------
// R23 aggregate: 2-chain (R15 geometry, measured best) + REQUEST MASKING.
// R22's 3-chain regression (+8% dur tracking +11% padded requests) showed the
// kernel is gather-REQUEST-throughput-bound, not latency-bound. The fused
// rm=max(rem0,rem1) loop made the shorter bucket issue ~25% pure zero-row
// request slots; guarding each chain's body with if(j<remX) (uniform per
// half-wave -> exec-mask divergence) eliminates those TA requests while
// keeping both chains' real gathers interleaved.
// ---------------------------------------------------------------------------
__global__ __launch_bounds__(256) void aggregate_kernel(const uint2* __restrict__ meta,
                                                        const int* __restrict__ sorted_src,
                                                        const ushort_t* __restrict__ xb,
                                                        ushort_t* __restrict__ h,
                                                        int r0, int cr) {
    int hw = threadIdx.x >> 5;                      // half-wave id 0..7
    int sl = threadIdx.x & 31;                      // lane covers 4 feats
    int g0 = blockIdx.x * 16 + hw * 2;              // first bucket
    int g1 = g0 + 1;
    int total = N_NODES * cr;
    if (g0 >= total) return;

    unsigned st0, mc0, st1 = 0u, mc1 = 0u;
    if (cr == NREL) {
        uint4 mm = *(const uint4*)&meta[(unsigned)g0];
        st0 = mm.x; mc0 = mm.y;
        st1 = mm.z; mc1 = mm.w;
    } else {
        int n0 = g0 / cr, rl0 = g0 - n0 * cr;
        unsigned key0 = (unsigned)n0 * NREL + (unsigned)(r0 + rl0);
        uint2 md0 = meta[key0];
        st0 = md0.x; mc0 = md0.y;
        if (g1 < total) {
            int n1 = g1 / cr, rl1 = g1 - n1 * cr;
            unsigned key1 = (unsigned)n1 * NREL + (unsigned)(r0 + rl1);
            uint2 md1 = meta[key1];
            st1 = md1.x; mc1 = md1.y;
        }
    }

    float a00 = 0.f, a01 = 0.f, a02 = 0.f, a03 = 0.f;
    float a10 = 0.f, a11 = 0.f, a12 = 0.f, a13 = 0.f;
    const char* xbase = (const char*)xb;
    unsigned slb = (unsigned)sl << 3;               // byte offset within row

    unsigned c0 = 0, c1 = 0;
    while (c0 < mc0 || c1 < mc1) {
        int sv0 = (c0 + (unsigned)sl < mc0) ? sorted_src[st0 + c0 + sl] : N_NODES;
        int sv1 = (c1 + (unsigned)sl < mc1) ? sorted_src[st1 + c1 + sl] : N_NODES;
        unsigned rem0 = (c0 < mc0) ? ((mc0 - c0 > 32u) ? 32u : (mc0 - c0)) : 0u;
        unsigned rem1 = (c1 < mc1) ? ((mc1 - c1 > 32u) ? 32u : (mc1 - c1)) : 0u;
        unsigned rm = rem0 > rem1 ? rem0 : rem1;
        for (unsigned j = 0; j < rm; j += 4) {
            if (j < rem0) {
                int s00 = __shfl(sv0, (int)j,     32);
                int s01 = __shfl(sv0, (int)j + 1, 32);
                int s02 = __shfl(sv0, (int)j + 2, 32);
                int s03 = __shfl(sv0, (int)j + 3, 32);
                uint2 d00 = *(const uint2*)(xbase + ((((unsigned)s00) << 8) | slb));
                uint2 d01 = *(const uint2*)(xbase + ((((unsigned)s01) << 8) | slb));
                uint2 d02 = *(const uint2*)(xbase + ((((unsigned)s02) << 8) | slb));
                uint2 d03 = *(const uint2*)(xbase + ((((unsigned)s03) << 8) | slb));
                a00 += (bf_lo(d00.x) + bf_lo(d01.x)) + (bf_lo(d02.x) + bf_lo(d03.x));
                a01 += (bf_hi(d00.x) + bf_hi(d01.x)) + (bf_hi(d02.x) + bf_hi(d03.x));
                a02 += (bf_lo(d00.y) + bf_lo(d01.y)) + (bf_lo(d02.y) + bf_lo(d03.y));
                a03 += (bf_hi(d00.y) + bf_hi(d01.y)) + (bf_hi(d02.y) + bf_hi(d03.y));
            }
            if (j < rem1) {
                int s10 = __shfl(sv1, (int)j,     32);
                int s11 = __shfl(sv1, (int)j + 1, 32);
                int s12 = __shfl(sv1, (int)j + 2, 32);
                int s13 = __shfl(sv1, (int)j + 3, 32);
                uint2 d10 = *(const uint2*)(xbase + ((((unsigned)s10) << 8) | slb));
                uint2 d11 = *(const uint2*)(xbase + ((((unsigned)s11) << 8) | slb));
                uint2 d12 = *(const uint2*)(xbase + ((((unsigned)s12) << 8) | slb));
                uint2 d13 = *(const uint2*)(xbase + ((((unsigned)s13) << 8) | slb));
                a10 += (bf_lo(d10.x) + bf_lo(d11.x)) + (bf_lo(d12.x) + bf_lo(d13.x));
                a11 += (bf_hi(d10.x) + bf_hi(d11.x)) + (bf_hi(d12.x) + bf_hi(d13.x));
                a12 += (bf_lo(d10.y) + bf_lo(d11.y)) + (bf_lo(d12.y) + bf_lo(d13.y));
                a13 += (bf_hi(d10.y) + bf_hi(d11.y)) + (bf_hi(d12.y) + bf_hi(d13.y));
            }
        }
        c0 += rem0;
        c1 += rem1;
    }

    float inv0 = 1.0f / fmaxf((float)mc0, 1.0f);
    unsigned lo0 = (unsigned)f2bf(a00 * inv0) | ((unsigned)f2bf(a01 * inv0) << 16);
    unsigned hi0 = (unsigned)f2bf(a02 * inv0) | ((unsigned)f2bf(a03 * inv0) << 16);
    ((uint2*)(h + (size_t)g0 * DIM))[sl] = make_uint2(lo0, hi0);
    if (g1 < total) {
        float inv1 = 1.0f / fmaxf((float)mc1, 1.0f);
        unsigned lo1 = (unsigned)f2bf(a10 * inv1) | ((unsigned)f2bf(a11 * inv1) << 16);
        unsigned hi1 = (unsigned)f2bf(a12 * inv1) | ((unsigned)f2bf(a13 * inv1) << 16);
        ((uint2*)(h + (size_t)g1 * DIM))[sl] = make_uint2(lo1, hi1);
    }
}

// ---------------------------------------------------------------------------
// LDS-staged MFMA GEMM + fused bias+LN+ReLU, register-prefetch across the
// rel loop (R18 exact form — best measured config, 249.6 total).
// ---------------------------------------------------------------------------
__global__ __launch_bounds__(512) void gemm_ln_kernel(const ushort_t* __restrict__ h,
                                                      int cr, int r0,
                                                      const ushort_t* __restrict__ xb,
                                                      const ushort_t* __restrict__ Bt,
                                                      int include_root,
                                                      const float* __restrict__ bias,
                                                      const float* __restrict__ gamma,
                                                      const float* __restrict__ beta,
                                                      float* __restrict__ out,
                                                      int accumulate, int do_ln) {
    __shared__ __align__(16) ushort_t As[128 * A_STRIDE];   // 34.8 KB
    __shared__ __align__(16) ushort_t Bs[128 * B_STRIDE];   // 34.8 KB

    int tid  = threadIdx.x;
    int w    = tid >> 6;          // 0..7
    int lane = tid & 63;
    int m    = lane & 15;
    int quad = lane >> 4;
    int n0   = blockIdx.x * 128;

    f32x4 acc[8];
#pragma unroll
    for (int j = 0; j < 8; ++j) acc[j] = (f32x4){0.f, 0.f, 0.f, 0.f};

    int nrel = cr + include_root;

    // per-thread staging chunk coords (4 chunks, 16B each)
    int rowc[4], chc[4];
#pragma unroll
    for (int p = 0; p < 4; ++p) {
        int c = tid + 512 * p;
        rowc[p] = c >> 4;
        chc[p]  = c & 15;
    }

    uintx4 ra[4], rb[4];
    auto loadRel = [&](int rr) {
        int rel = (rr < cr) ? (r0 + rr) : NREL;
#pragma unroll
        for (int p = 0; p < 4; ++p) {
            rb[p] = *(const uintx4*)(Bt + ((size_t)rel * DIM + rowc[p]) * DIM + chc[p] * 8);
            uintx4 v = (uintx4){0u, 0u, 0u, 0u};
            int node = n0 + rowc[p];
            if (node < N_NODES) {
                const ushort_t* src = (rr < cr)
                    ? (h + ((size_t)node * cr + rr) * DIM)
                    : (xb + (size_t)node * DIM);
                v = *(const uintx4*)(src + chc[p] * 8);
            }
            ra[p] = v;
        }
    };
    auto writeLDS = [&]() {
#pragma unroll
        for (int p = 0; p < 4; ++p) {
            *(uintx4*)&Bs[rowc[p] * B_STRIDE + chc[p] * 8] = rb[p];
            *(uintx4*)&As[rowc[p] * A_STRIDE + chc[p] * 8] = ra[p];
        }
    };

    // prologue: stage rel 0
    loadRel(0);
    writeLDS();
    __syncthreads();

    for (int rr = 0; rr < nrel; ++rr) {
        // issue next rel's loads BEFORE the MFMA phase (latency hides under MFMA)
        if (rr + 1 < nrel) loadRel(rr + 1);

        // ---- 32 MFMA per wave ----
#pragma unroll
        for (int t = 0; t < 4; ++t) {
            short8 af = *(const short8*)&As[(w * 16 + m) * A_STRIDE + t * 32 + quad * 8];
#pragma unroll
            for (int j = 0; j < 8; ++j) {
                short8 bf = *(const short8*)&Bs[(j * 16 + m) * B_STRIDE + t * 32 + quad * 8];
                acc[j] = __builtin_amdgcn_mfma_f32_16x16x32_bf16(af, bf, acc[j], 0, 0, 0);
            }
        }
        __syncthreads();                 // all LDS reads of this rel done
        if (rr + 1 < nrel) {
            writeLDS();                  // regs (load-complete by waitcnt) -> LDS
            __syncthreads();             // LDS ready for next rel
        }
    }

    // ---- epilogue ----
    if (do_ln) {
        float bj[8], gj[8], btj[8];
#pragma unroll
        for (int j = 0; j < 8; ++j) {
            bj[j]  = bias[j * 16 + m];
            gj[j]  = gamma[j * 16 + m];
            btj[j] = beta[j * 16 + m];
        }
#pragma unroll
        for (int i = 0; i < 4; ++i) {
            float s = 0.f, sq = 0.f;
#pragma unroll
            for (int j = 0; j < 8; ++j) {
                float v = acc[j][i] + bj[j];
                s  += v;
                sq += v * v;
            }
#pragma unroll
            for (int off = 1; off < 16; off <<= 1) {
                s  += __shfl_xor(s, off, 64);
                sq += __shfl_xor(sq, off, 64);
            }
            float mean = s * (1.0f / DIM);
            float var  = sq * (1.0f / DIM) - mean * mean;
            float rstd = rsqrtf(var + LN_EPS);
            int node = n0 + w * 16 + quad * 4 + i;
            if (node < N_NODES) {
#pragma unroll
                for (int j = 0; j < 8; ++j) {
                    float v = acc[j][i] + bj[j];
                    v = (v - mean) * rstd * gj[j] + btj[j];
                    out[(size_t)node * DIM + j * 16 + m] = fmaxf(v, 0.f);
                }
            }
        }
    } else {
#pragma unroll
        for (int i = 0; i < 4; ++i) {
            int node = n0 + w * 16 + quad * 4 + i;
            if (node < N_NODES) {
#pragma unroll
                for (int j = 0; j < 8; ++j) {
                    size_t o = (size_t)node * DIM + j * 16 + m;
                    float v = acc[j][i];
                    if (accumulate) v += out[o];
                    out[o] = v;
                }
            }
        }
    }
}

// ---------------------------------------------------------------------------
// Standalone bias + LayerNorm + ReLU (fallback for chunked path).
// ---------------------------------------------------------------------------
__global__ __launch_bounds__(256) void ln_kernel(float* __restrict__ out,
                                                 const float* __restrict__ bias,
                                                 const float* __restrict__ gamma,
                                                 const float* __restrict__ beta) {
    int row  = blockIdx.x * 4 + (threadIdx.x >> 6);
    int lane = threadIdx.x & 63;
    if (row >= N_NODES) return;
    float2 v = *(float2*)(out + (size_t)row * DIM + lane * 2);
    float2 bi = *(const float2*)(bias + lane * 2);
    v.x += bi.x;
    v.y += bi.y;
    float s  = v.x + v.y;
    float sq = v.x * v.x + v.y * v.y;
#pragma unroll
    for (int off = 32; off > 0; off >>= 1) {
        s  += __shfl_xor(s, off, 64);
        sq += __shfl_xor(sq, off, 64);
    }
    float mean = s * (1.0f / DIM);
    float var  = sq * (1.0f / DIM) - mean * mean;
    float rstd = rsqrtf(var + LN_EPS);
    float2 g = *(const float2*)(gamma + lane * 2);
    float2 b = *(const float2*)(beta + lane * 2);
    v.x = fmaxf((v.x - mean) * rstd * g.x + b.x, 0.f);
    v.y = fmaxf((v.y - mean) * rstd * g.y + b.y, 0.f);
    *(float2*)(out + (size_t)row * DIM + lane * 2) = v;
}

// ---------------------------------------------------------------------------
extern "C" void kernel_launch(void* const* d_in, const int* in_sizes, int n_in,
                              void* d_out, int out_size, void* d_ws, size_t ws_size,
                              hipStream_t stream) {
    const float* x      = (const float*)d_in[0];
    const int*   ei     = (const int*)d_in[1];
    const int*   et     = (const int*)d_in[2];
    const float* W_rel  = (const float*)d_in[4];
    const float* W_root = (const float*)d_in[5];
    const float* bias   = (const float*)d_in[6];
    const float* gamma  = (const float*)d_in[7];
    const float* beta   = (const float*)d_in[8];
    float*       out    = (float*)d_out;

    // ---- workspace layout ----
    char* ws = (char*)d_ws;
    size_t off = 0;
    auto alloc = [&](size_t bytes) { char* p = ws + off; off = (off + bytes + 255) & ~(size_t)255; return p; };
    unsigned* block_hist = (unsigned*)alloc((size_t)NBIN * BH_STRIDE * 4);   // 2.5 MB
    unsigned* bin_tot    = (unsigned*)alloc((size_t)NBIN * 4);
    unsigned* bin_base   = (unsigned*)alloc((size_t)NBIN * 4);
    unsigned* rec        = (unsigned*)alloc((size_t)N_EDGES * 4);            // 6.4 MB
    uint2*    meta       = (uint2*)alloc((size_t)NKEYS * 8);                 // 3.2 MB
    int*      sorted_src = (int*)alloc((size_t)N_EDGES * 4);                 // 6.4 MB
    ushort_t* Bt         = (ushort_t*)alloc((size_t)9 * DIM * DIM * 2);
    ushort_t* xb         = (ushort_t*)alloc((size_t)(N_NODES + 1) * DIM * 2);  // +1 zero row
    size_t fixedOff = off;
    ushort_t* h = (ushort_t*)(ws + fixedOff);
    size_t availB = ws_size > fixedOff ? ws_size - fixedOff : 0;
    size_t perRel = (size_t)N_NODES * DIM * 2;   // 12.8 MB per relation (bf16)
    int chunkR = (int)(availB / perRel);
    if (chunkR > NREL) chunkR = NREL;
    if (chunkR < 1)    chunkR = 1;

    // ---- atomic-free two-level counting sort + prep ----
    prep_kernel<<<PA_BLOCKS + XB_BLOCKS + BT_BLOCKS + 1, 256, 0, stream>>>(
        x, xb, W_rel, W_root, Bt, ei, et, block_hist);
    scanA2_kernel<<<NBIN, 256, 0, stream>>>(block_hist, bin_tot);
    scanA3_kernel<<<1, 512, 0, stream>>>(bin_tot, bin_base);
    passB_kernel<<<PA_BLOCKS, 256, 0, stream>>>(ei, et, block_hist, bin_base, rec);
    passC_kernel<<<NBIN, 256, 0, stream>>>(rec, bin_base, bin_tot, meta, sorted_src);

    int gemmGrid = (N_NODES + 127) / 128;   // 391 blocks

    if (chunkR >= NREL) {
        int nbuck = N_NODES * NREL;
        aggregate_kernel<<<(nbuck + 15) / 16, 256, 0, stream>>>(meta, sorted_src,
                                                                xb, h, 0, NREL);
        gemm_ln_kernel<<<gemmGrid, 512, 0, stream>>>(h, NREL, 0, xb, Bt, 1,
                                                     bias, gamma, beta, out, 0, 1);
    } else {
        for (int r0 = 0; r0 < NREL; r0 += chunkR) {
            int cr = (NREL - r0 < chunkR) ? (NREL - r0) : chunkR;
            int nbuck = N_NODES * cr;
            aggregate_kernel<<<(nbuck + 15) / 16, 256, 0, stream>>>(meta, sorted_src,
                                                                    xb, h, r0, cr);
            int include_root = (r0 + cr == NREL) ? 1 : 0;
            gemm_ln_kernel<<<gemmGrid, 512, 0, stream>>>(h, cr, r0, xb, Bt, include_root,
                                                         bias, gamma, beta, out,
                                                         r0 > 0 ? 1 : 0, 0);
        }
        ln_kernel<<<(N_NODES + 3) / 4, 256, 0, stream>>>(out, bias, gamma, beta);
    }
}